// Round 10
// baseline (241.771 us; speedup 1.0000x reference)
//
#include <hip/hip_runtime.h>
#include <math.h>

#define D_MODEL 1024
#define D_INNER 2048
#define D_STATE 64
#define SEQ     2048
#define BATCH   2
#define NROWS   (BATCH*SEQ)   // 4096

typedef unsigned short ushort_t;
typedef unsigned int uint_t;

__device__ __forceinline__ float silu_f(float x) { return x / (1.f + __expf(-x)); }
__device__ __forceinline__ ushort_t f2bf(float f) {
    uint_t u = __float_as_uint(f);
    uint_t r = (u + 0x7FFFu + ((u >> 16) & 1u)) >> 16;   // RNE
    return (ushort_t)r;
}
__device__ __forceinline__ float bf2f(ushort_t u) {
    return __uint_as_float(((uint_t)u) << 16);
}

typedef __attribute__((address_space(1))) const void gvoid_t;
typedef __attribute__((address_space(3))) void lvoid_t;

template<int N> __device__ __forceinline__ void wait_vmcnt() {
    if constexpr (N == 0)      asm volatile("s_waitcnt vmcnt(0)" ::: "memory");
    else if constexpr (N == 4) asm volatile("s_waitcnt vmcnt(4)" ::: "memory");
    else if constexpr (N == 6) asm volatile("s_waitcnt vmcnt(6)" ::: "memory");
    else static_assert(N == 0 || N == 4 || N == 6, "unsupported vmcnt");
}

// ---------------------------------------------------------------------------
// Batched f32 -> bf16 conversion: 4 (src,dst) ranges in one launch.
// ---------------------------------------------------------------------------
__global__ __launch_bounds__(256) void cvt4_kernel(
    const float* __restrict__ s0, ushort_t* __restrict__ d0, int b0,
    const float* __restrict__ s1, ushort_t* __restrict__ d1, int b1,
    const float* __restrict__ s2, ushort_t* __restrict__ d2, int b2,
    const float* __restrict__ s3, ushort_t* __restrict__ d3, int b3)
{
    int blk = blockIdx.x;
    const float* s; ushort_t* d;
    if (blk < b0)               { s = s0; d = d0; }
    else if (blk < b0 + b1)     { s = s1; d = d1; blk -= b0; }
    else if (blk < b0 + b1 + b2){ s = s2; d = d2; blk -= b0 + b1; }
    else                        { s = s3; d = d3; blk -= b0 + b1 + b2; }
    int i = (blk * 256 + threadIdx.x) * 4;
    float4 v = *reinterpret_cast<const float4*>(s + i);
    ushort4 o;
    o.x = f2bf(v.x); o.y = f2bf(v.y); o.z = f2bf(v.z); o.w = f2bf(v.w);
    *reinterpret_cast<ushort4*>(d + i) = o;
}

// ---------------------------------------------------------------------------
// bf16 MFMA GEMM, depth-3 pipelined, counted vmcnt, ONE barrier per K-iter,
// CONFLICT-FREE LDS layout: each 16-row x 32-k block stored k-major so a
// wave's fragment ds_read is base + lane*16B (contiguous 1KB, 0 conflicts).
// Staging pre-permutes the per-lane GLOBAL source (lane l -> row 16i+(l&15),
// k-chunk l>>4); global_load_lds writes linearly (rule #21 compliant).
// C(M,N) = A(M,K) * W(N,K)^T + bias, tile BMt x BNt x BKt, 4 waves 2x2.
// MODE 0: out0 = f32 C (out_proj);  MODE 1: in_proj split epilogue.
// ---------------------------------------------------------------------------
template <int MODE, int BMt, int BNt, int BKt>
__global__ __launch_bounds__(256) void gemm_pipe(
    const ushort_t* __restrict__ Abf, const ushort_t* __restrict__ Wbf,
    const float* __restrict__ bias,
    void* __restrict__ out0, ushort_t* __restrict__ out1,
    int M, int N, int K)
{
    using bf16x8 = __attribute__((ext_vector_type(8))) short;
    using f32x4  = __attribute__((ext_vector_type(4))) float;

    constexpr int KH   = BKt / 32;                 // 32-wide k-halves per tile
    constexpr int MF   = BMt / 32;                 // m-frags per wave
    constexpr int NF   = BNt / 32;                 // n-frags per wave
    constexpr int ABLK = (BMt / 16) * KH;          // A 1KB staging blocks
    constexpr int NBLK = ((BMt + BNt) / 16) * KH;  // total 1KB blocks per tile
    constexpr int TILE = (BMt + BNt) * BKt;        // ushorts per LDS buffer
    constexpr int L    = NBLK / 4;                 // gload_lds per wave per tile

    __shared__ ushort_t buf[3][TILE];

    const int tid  = threadIdx.x;
    const int lane = tid & 63;
    const int wid  = tid >> 6;
    const int bm   = blockIdx.y * BMt;
    const int bn   = blockIdx.x * BNt;
    const int wr   = (wid >> 1) * (BMt / 2);
    const int wc   = (wid & 1) * (BNt / 2);
    const int r16  = lane & 15;       // frag row / staging row-in-block
    const int g    = lane >> 4;       // frag k-chunk / staging k-chunk

    f32x4 acc[MF][NF] = {};

    auto stage = [&](int p, int k0) {
        #pragma unroll
        for (int i = wid; i < NBLK; i += 4) {
            const ushort_t* gsrc;
            if (i < ABLK) {
                int rb = i / KH, kh = i % KH;
                gsrc = Abf + (size_t)(bm + 16 * rb + r16) * K + k0 + kh * 32 + g * 8;
            } else {
                int j = i - ABLK;
                int rb = j / KH, kh = j % KH;
                gsrc = Wbf + (size_t)(bn + 16 * rb + r16) * K + k0 + kh * 32 + g * 8;
            }
            __builtin_amdgcn_global_load_lds((gvoid_t*)gsrc, (lvoid_t*)(&buf[p][i * 512]), 16, 0, 0);
        }
    };

    const int NT = K / BKt;   // >= 3 for both GEMMs
    stage(0, 0);
    stage(1, BKt);
    wait_vmcnt<L>();                   // tile 0 landed (tile 1 in flight)
    __builtin_amdgcn_s_barrier();

    int cur = 0, s2 = 2;
    for (int t = 0; t < NT; ++t) {
        if (t + 2 < NT) stage(s2, (t + 2) * BKt);   // issue-early

        const ushort_t* Tb = &buf[cur][0];
        bf16x8 af[MF][KH], bfr[NF][KH];
        #pragma unroll
        for (int kk = 0; kk < KH; ++kk) {
            #pragma unroll
            for (int m = 0; m < MF; ++m)
                af[m][kk] = *reinterpret_cast<const bf16x8*>(
                    &Tb[(((wr >> 4) + m) * KH + kk) * 512 + lane * 8]);
            #pragma unroll
            for (int n = 0; n < NF; ++n)
                bfr[n][kk] = *reinterpret_cast<const bf16x8*>(
                    &Tb[BMt * BKt + (((wc >> 4) + n) * KH + kk) * 512 + lane * 8]);
        }

        #pragma unroll
        for (int kk = 0; kk < KH; ++kk)
            #pragma unroll
            for (int m = 0; m < MF; ++m)
                #pragma unroll
                for (int n = 0; n < NF; ++n)
                    acc[m][n] = __builtin_amdgcn_mfma_f32_16x16x32_bf16(af[m][kk], bfr[n][kk], acc[m][n], 0, 0, 0);

        if (t + 1 < NT) {
            if (t + 2 < NT) wait_vmcnt<L>();   // tile t+1 landed; t+2 stays in flight
            else            wait_vmcnt<0>();
            __builtin_amdgcn_s_barrier();
        }
        cur = (cur + 1 == 3) ? 0 : cur + 1;
        s2  = (s2  + 1 == 3) ? 0 : s2  + 1;
    }

    #pragma unroll
    for (int m = 0; m < MF; ++m) {
        int row0 = bm + wr + m * 16 + g * 4;
        #pragma unroll
        for (int n = 0; n < NF; ++n) {
            int col = bn + wc + n * 16 + r16;
            float b = bias[col];
            if (MODE == 0) {
                float* O = (float*)out0;
                #pragma unroll
                for (int jj = 0; jj < 4; ++jj)
                    O[(size_t)(row0 + jj) * N + col] = acc[m][n][jj] + b;
            } else {
                if (bn < D_INNER) {
                    ushort_t* O = (ushort_t*)out0;
                    #pragma unroll
                    for (int jj = 0; jj < 4; ++jj)
                        O[(size_t)(row0 + jj) * D_INNER + col] = f2bf(acc[m][n][jj] + b);
                } else {
                    int c2 = col - D_INNER;
                    #pragma unroll
                    for (int jj = 0; jj < 4; ++jj)
                        out1[(size_t)(row0 + jj) * D_INNER + c2] = f2bf(silu_f(acc[m][n][jj] + b));
                }
            }
        }
    }
}

// ---------------------------------------------------------------------------
// Causal depthwise conv (D_CONV=4) + SiLU.  bf16 in, bf16 out.
// ---------------------------------------------------------------------------
__global__ __launch_bounds__(256) void conv_silu_kernel(
    const ushort_t* __restrict__ xssm,
    const float* __restrict__ conv_w,
    const float* __restrict__ conv_b,
    ushort_t* __restrict__ xc)
{
    int idx4 = blockIdx.x * 256 + threadIdx.x;
    if (idx4 >= NROWS * D_INNER / 4) return;
    size_t e = (size_t)idx4 * 4;
    int c   = (int)(e % D_INNER);
    int row = (int)(e / D_INNER);
    int s = row % SEQ;

    float4 wv[4];
    #pragma unroll
    for (int cc = 0; cc < 4; ++cc)
        wv[cc] = *reinterpret_cast<const float4*>(conv_w + (c + cc) * 4);
    float4 bv = *reinterpret_cast<const float4*>(conv_b + c);
    float acc[4] = {bv.x, bv.y, bv.z, bv.w};

    #pragma unroll
    for (int dt = 0; dt < 4; ++dt) {
        if (s >= dt) {
            ushort4 xv = *reinterpret_cast<const ushort4*>(xssm + (size_t)(row - dt) * D_INNER + c);
            acc[0] += (&wv[0].x)[3 - dt] * bf2f(xv.x);
            acc[1] += (&wv[1].x)[3 - dt] * bf2f(xv.y);
            acc[2] += (&wv[2].x)[3 - dt] * bf2f(xv.z);
            acc[3] += (&wv[3].x)[3 - dt] * bf2f(xv.w);
        }
    }
    ushort4 h;
    h.x = f2bf(silu_f(acc[0]));
    h.y = f2bf(silu_f(acc[1]));
    h.z = f2bf(silu_f(acc[2]));
    h.w = f2bf(silu_f(acc[3]));
    *reinterpret_cast<ushort4*>(xc + e) = h;
}

// ---------------------------------------------------------------------------
// XB = xconv (4096,2048) @ B(64,2048)^T -> (4096,64), bf16 MFMA.
// ---------------------------------------------------------------------------
#define BK 32
__global__ __launch_bounds__(128) void xb_mfma(
    const ushort_t* __restrict__ xc, const ushort_t* __restrict__ Bw,
    float* __restrict__ xb)
{
    using bf16x8 = __attribute__((ext_vector_type(8))) short;
    using f32x4  = __attribute__((ext_vector_type(4))) float;

    __shared__ ushort_t As[32 * BK];   // 2 KB
    __shared__ ushort_t Bs[64 * BK];   // 4 KB

    const int tid  = threadIdx.x;
    const int lane = tid & 63;
    const int wid  = tid >> 6;
    const int bm   = blockIdx.x * 32;
    const int r16  = lane & 15;
    const int g    = lane >> 4;
    const int srow = lane >> 2;
    const int scol = (lane & 3) * 8;

    f32x4 acc[4] = {};

    for (int k0 = 0; k0 < D_INNER; k0 += BK) {
        const ushort_t* ga = xc + (size_t)(bm + 16 * wid + srow) * D_INNER + k0 + scol;
        __builtin_amdgcn_global_load_lds((gvoid_t*)ga, (lvoid_t*)(As + wid * 512), 16, 0, 0);
        #pragma unroll
        for (int ii = 0; ii < 2; ++ii) {
            int i = wid * 2 + ii;
            const ushort_t* gb = Bw + (size_t)(16 * i + srow) * D_INNER + k0 + scol;
            __builtin_amdgcn_global_load_lds((gvoid_t*)gb, (lvoid_t*)(Bs + i * 512), 16, 0, 0);
        }
        __syncthreads();

        bf16x8 a = *reinterpret_cast<const bf16x8*>(&As[(wid * 16 + r16) * BK + g * 8]);
        #pragma unroll
        for (int n = 0; n < 4; ++n) {
            bf16x8 bv = *reinterpret_cast<const bf16x8*>(&Bs[(n * 16 + r16) * BK + g * 8]);
            acc[n] = __builtin_amdgcn_mfma_f32_16x16x32_bf16(a, bv, acc[n], 0, 0, 0);
        }
        __syncthreads();
    }

    #pragma unroll
    for (int n = 0; n < 4; ++n) {
        int col  = n * 16 + r16;
        int row0 = bm + wid * 16 + g * 4;
        #pragma unroll
        for (int jj = 0; jj < 4; ++jj)
            xb[(size_t)(row0 + jj) * D_STATE + col] = acc[n][jj];
    }
}

// ---------------------------------------------------------------------------
// Speculative chunked tanh scan (overlap-save), C=W=16 (32 serial steps).
// ---------------------------------------------------------------------------
#define SCAN_C 16
#define SCAN_W 16
#define NCHUNK (SEQ / SCAN_C)   // 128

__global__ __launch_bounds__(64) void scan_kernel(const float* __restrict__ xb,
                                                  const float* __restrict__ A,
                                                  float* __restrict__ hall)
{
    using f32x4 = __attribute__((ext_vector_type(4))) float;

    __shared__ float xs[(SCAN_C + SCAN_W) * D_STATE];   // 8 KB
    __shared__ float hs[D_STATE];

    const int blk = blockIdx.x;
    const int b = blk >> 7;          // / NCHUNK
    const int c = blk & (NCHUNK - 1);
    const int j = threadIdx.x;

    const int t0     = (c == 0) ? 0 : (c * SCAN_C - SCAN_W);
    const int warm   = c * SCAN_C - t0;        // 0 or 16
    const int nsteps = warm + SCAN_C;          // 16 or 32

    f32x4 areg[16];
    {
        const f32x4* arow = reinterpret_cast<const f32x4*>(A + j * D_STATE);
        #pragma unroll
        for (int q = 0; q < 16; ++q) areg[q] = arow[q];
    }

    const float* src = xb   + ((size_t)b * SEQ + t0) * D_STATE;
    float*       dst = hall + ((size_t)b * SEQ + c * SCAN_C) * D_STATE;

    const int nld = nsteps * D_STATE / 256;    // 4 or 8 x 1KB
    for (int i = 0; i < nld; ++i)
        __builtin_amdgcn_global_load_lds((gvoid_t*)(src + i * 256 + j * 4),
                                         (lvoid_t*)(&xs[i * 256]), 16, 0, 0);
    asm volatile("s_waitcnt vmcnt(0)" ::: "memory");

    hs[j] = 0.f;
    float h = 0.f;
    const f32x4* hp = reinterpret_cast<const f32x4*>(hs);

#define SCAN_STEP(t)                                                     \
    {                                                                    \
        float xv = xs[(t) * D_STATE + j];                                \
        f32x4 a0 = {xv, 0.f, 0.f, 0.f}, a1 = {0.f, 0.f, 0.f, 0.f};      \
        _Pragma("unroll")                                                \
        for (int q = 0; q < 16; q += 2) {                                \
            a0 += areg[q + 0] * hp[q + 0];                               \
            a1 += areg[q + 1] * hp[q + 1];                               \
        }                                                                \
        f32x4 s4 = a0 + a1;                                              \
        float s = (s4[0] + s4[1]) + (s4[2] + s4[3]);                     \
        float e = __expf(2.f * s);                                       \
        h = 1.f - 2.f * __builtin_amdgcn_rcpf(e + 1.f);                  \
        hs[j] = h;                                                       \
    }

    for (int t = 0; t < warm; ++t) {
        SCAN_STEP(t);
    }
    for (int t = warm; t < nsteps; ++t) {
        SCAN_STEP(t);
        dst[(size_t)(t - warm) * D_STATE + j] = h;
    }
#undef SCAN_STEP
}

// ---------------------------------------------------------------------------
// y = H @ C^T + xconv*D; x_out(bf16) = y * silu_gate(bf16)
// 2-D grid: (NROWS/16) x (D_INNER/256) = 2048 blocks.
// ---------------------------------------------------------------------------
__global__ __launch_bounds__(256) void ymul_kernel(
    const float* __restrict__ hall,
    const float* __restrict__ Cw,
    const float* __restrict__ Dv,
    const ushort_t* __restrict__ xc,
    const ushort_t* __restrict__ xg,
    ushort_t* __restrict__ xout)
{
    __shared__ float hs[16][D_STATE];
    int row0 = blockIdx.x * 16;
    int col  = blockIdx.y * 256 + threadIdx.x;
    int tid = threadIdx.x;
    const float4* src = reinterpret_cast<const float4*>(hall + (size_t)row0 * D_STATE);
    float4* dst = reinterpret_cast<float4*>(&hs[0][0]);
    dst[tid] = src[tid];    // 256 float4 = 16 rows x 64
    __syncthreads();

    float creg[D_STATE];
    #pragma unroll
    for (int k = 0; k < D_STATE; k += 4) {
        float4 v = *reinterpret_cast<const float4*>(Cw + (size_t)col * D_STATE + k);
        creg[k] = v.x; creg[k + 1] = v.y; creg[k + 2] = v.z; creg[k + 3] = v.w;
    }
    float dv = Dv[col];
    #pragma unroll 4
    for (int r = 0; r < 16; ++r) {
        float a0 = 0, a1 = 0, a2 = 0, a3 = 0;
        #pragma unroll
        for (int k = 0; k < D_STATE; k += 4) {
            a0 += hs[r][k + 0] * creg[k + 0];
            a1 += hs[r][k + 1] * creg[k + 1];
            a2 += hs[r][k + 2] * creg[k + 2];
            a3 += hs[r][k + 3] * creg[k + 3];
        }
        size_t idx = (size_t)(row0 + r) * D_INNER + col;
        float y = (a0 + a1) + (a2 + a3) + bf2f(xc[idx]) * dv;
        xout[idx] = f2bf(y * bf2f(xg[idx]));
    }
}

// ---------------------------------------------------------------------------
extern "C" void kernel_launch(void* const* d_in, const int* in_sizes, int n_in,
                              void* d_out, int out_size, void* d_ws, size_t ws_size,
                              hipStream_t stream)
{
    const float* x          = (const float*)d_in[0];
    const float* in_proj_w  = (const float*)d_in[1];
    const float* in_proj_b  = (const float*)d_in[2];
    const float* conv_w     = (const float*)d_in[3];
    const float* conv_b     = (const float*)d_in[4];
    const float* A          = (const float*)d_in[5];
    const float* B          = (const float*)d_in[6];
    const float* C          = (const float*)d_in[7];
    const float* D          = (const float*)d_in[8];
    const float* out_proj_w = (const float*)d_in[9];
    const float* out_proj_b = (const float*)d_in[10];
    float* out = (float*)d_out;

    char* ws = (char*)d_ws;
    ushort_t* xg_bf   = (ushort_t*)(ws + 0);             // 16,777,216
    ushort_t* xc_bf   = (ushort_t*)(ws + 16777216);      // 16,777,216
    ushort_t* xssm_bf = (ushort_t*)(ws + 33554432);      // 16,777,216 (dead after conv)
    ushort_t* x_bf    = (ushort_t*)(ws + 50331648);      //  8,388,608 (dead after in_proj)
    ushort_t* w1_bf   = (ushort_t*)(ws + 58720256);      //  8,388,608 (dead after in_proj)
    ushort_t* xout_bf = (ushort_t*)(ws + 50331648);      // 16,777,216 (reuses x_bf+w1_bf)
    ushort_t* w2_bf   = (ushort_t*)(ws + 67108864);      //  4,194,304
    ushort_t* B_bf    = (ushort_t*)(ws + 71303168);      //    262,144
    float*    xb      = (float*)(ws + 71565312);         //  1,048,576
    float*    hall    = (float*)(ws + 72613888);         //  1,048,576

    // 1. all f32 -> bf16 conversions, one launch
    {
        int b0 = NROWS * D_MODEL / 1024;
        int b1 = 2 * D_INNER * D_MODEL / 1024;
        int b2 = D_MODEL * D_INNER / 1024;
        int b3 = D_STATE * D_INNER / 1024;
        cvt4_kernel<<<b0 + b1 + b2 + b3, 256, 0, stream>>>(
            x, x_bf, b0, in_proj_w, w1_bf, b1, out_proj_w, w2_bf, b2, B, B_bf, b3);
    }
    // 2. in_proj GEMM (depth-3, 128x128x32, conflict-free LDS)
    {
        dim3 grid(2 * D_INNER / 128, NROWS / 128);
        gemm_pipe<1, 128, 128, 32><<<grid, 256, 0, stream>>>(x_bf, w1_bf, in_proj_b,
                                                             xssm_bf, xg_bf, NROWS, 2 * D_INNER, D_MODEL);
    }
    // 3. conv + silu -> bf16
    conv_silu_kernel<<<NROWS * D_INNER / 1024, 256, 0, stream>>>(xssm_bf, conv_w, conv_b, xc_bf);
    // 4. XB via bf16 MFMA
    xb_mfma<<<NROWS / 32, 128, 0, stream>>>(xc_bf, B_bf, xb);
    // 5. speculative chunked scan (C=W=16)
    scan_kernel<<<BATCH * NCHUNK, 64, 0, stream>>>(xb, A, hall);
    // 6. y + D-skip + gate multiply -> bf16 x_out (2-D grid)
    {
        dim3 grid(NROWS / 16, D_INNER / 256);
        ymul_kernel<<<grid, 256, 0, stream>>>(hall, C, D, xc_bf, xg_bf, xout_bf);
    }
    // 7. out_proj GEMM (depth-3, 128x64x64, conflict-free LDS)
    {
        dim3 grid(D_MODEL / 64, NROWS / 128);
        gemm_pipe<0, 128, 64, 64><<<grid, 256, 0, stream>>>(xout_bf, w2_bf, out_proj_b,
                                                            out, nullptr, NROWS, D_MODEL, D_INNER);
    }
}

// Round 11
// 203.852 us; speedup vs baseline: 1.1860x; 1.1860x over previous
//
#include <hip/hip_runtime.h>
#include <math.h>

#define D_MODEL 1024
#define D_INNER 2048
#define D_STATE 64
#define SEQ     2048
#define BATCH   2
#define NROWS   (BATCH*SEQ)   // 4096

typedef unsigned short ushort_t;
typedef unsigned int uint_t;

__device__ __forceinline__ float silu_f(float x) { return x / (1.f + __expf(-x)); }
__device__ __forceinline__ ushort_t f2bf(float f) {
    uint_t u = __float_as_uint(f);
    uint_t r = (u + 0x7FFFu + ((u >> 16) & 1u)) >> 16;   // RNE
    return (ushort_t)r;
}
__device__ __forceinline__ float bf2f(ushort_t u) {
    return __uint_as_float(((uint_t)u) << 16);
}

typedef __attribute__((address_space(1))) const void gvoid_t;
typedef __attribute__((address_space(3))) void lvoid_t;

template<int N> __device__ __forceinline__ void wait_vmcnt() {
    if constexpr (N == 0)      asm volatile("s_waitcnt vmcnt(0)" ::: "memory");
    else if constexpr (N == 2) asm volatile("s_waitcnt vmcnt(2)" ::: "memory");
    else if constexpr (N == 3) asm volatile("s_waitcnt vmcnt(3)" ::: "memory");
    else if constexpr (N == 4) asm volatile("s_waitcnt vmcnt(4)" ::: "memory");
    else static_assert(N == 0 || N == 2 || N == 3 || N == 4, "unsupported vmcnt");
}

// ---------------------------------------------------------------------------
// Batched f32 -> bf16 conversion: 4 (src,dst) ranges in one launch.
// ---------------------------------------------------------------------------
__global__ __launch_bounds__(256) void cvt4_kernel(
    const float* __restrict__ s0, ushort_t* __restrict__ d0, int b0,
    const float* __restrict__ s1, ushort_t* __restrict__ d1, int b1,
    const float* __restrict__ s2, ushort_t* __restrict__ d2, int b2,
    const float* __restrict__ s3, ushort_t* __restrict__ d3, int b3)
{
    int blk = blockIdx.x;
    const float* s; ushort_t* d;
    if (blk < b0)               { s = s0; d = d0; }
    else if (blk < b0 + b1)     { s = s1; d = d1; blk -= b0; }
    else if (blk < b0 + b1 + b2){ s = s2; d = d2; blk -= b0 + b1; }
    else                        { s = s3; d = d3; blk -= b0 + b1 + b2; }
    int i = (blk * 256 + threadIdx.x) * 4;
    float4 v = *reinterpret_cast<const float4*>(s + i);
    ushort4 o;
    o.x = f2bf(v.x); o.y = f2bf(v.y); o.z = f2bf(v.z); o.w = f2bf(v.w);
    *reinterpret_cast<ushort4*>(d + i) = o;
}

// ---------------------------------------------------------------------------
// in_proj GEMM: 8-phase-style 256x256x64 schedule (T2+T3+T4+T5).
// 512 threads = 8 waves (2 row x 4 col). Grid 16x16=256 (1 block/CU).
// LDS 128KB dynamic: [dbuf2][op A/B][half2][16KB]; half = 128 rows x 64 k.
// Half stored as [8 subR][2 subC] subtiles of [16r][32k] bf16 (1KB each),
// inner bytes XOR-swizzled: byte ^= ((r>>3)&1)<<5 ^ ((r>>1)&3)<<4  -> a wave
// frag ds_read_b128 is a perfect 64-slot permutation (0 bank conflicts).
// Stage: global SOURCE chunk pre-permuted (same involution), DMA dest linear,
// quarter-wave global coalescing preserved (rows contiguous 64B).
// Per K-tile: 4 phases = C-quadrants (qr,qc); each: counted vmcnt(4) ->
// barrier -> ds_read (12/4/8/0, B cached) -> issue 1 half prefetch (3-phase
// lead, order A0,B0,B1,A1) -> setprio(1) -> 16 MFMA -> setprio(0).
// vmcnt never drains to 0 except final tile.
// ---------------------------------------------------------------------------
__global__ __launch_bounds__(512, 2) void gemm8p_inproj(
    const ushort_t* __restrict__ Abf, const ushort_t* __restrict__ Wbf,
    const float* __restrict__ bias,
    ushort_t* __restrict__ out_x, ushort_t* __restrict__ out_g)
{
    using bf16x8 = __attribute__((ext_vector_type(8))) short;
    using f32x4  = __attribute__((ext_vector_type(4))) float;

    extern __shared__ char smem[];   // 131072 bytes

    const int tid  = threadIdx.x;
    const int lane = tid & 63;
    const int wid  = tid >> 6;        // 0..7
    const int wm   = wid >> 2;        // 0..1  (row half of quadrant)
    const int wn   = wid & 3;         // 0..3  (col quarter of quadrant)
    const int r16  = lane & 15;
    const int g    = lane >> 4;

    // XCD-aware bijective swizzle over 256 blocks (8 XCDs x 32)
    const int bid = blockIdx.x;
    const int swz = (bid & 7) * 32 + (bid >> 3);
    const int bm  = (swz >> 4) * 256;
    const int bn  = (swz & 15) * 256;

    // read-side swizzled inner offset (bytes within 1KB subtile)
    const int rdswz = (r16 * 64 + g * 16) ^ (((r16 >> 3) & 1) << 5) ^ (((r16 >> 1) & 3) << 4);
    // stage-side: pre-permuted global k-chunk for this lane (ushort units)
    const int srow4  = lane >> 2;
    const int schunk = (((lane & 3) ^ ((lane >> 3) & 3) ^ (((lane >> 5) & 1) << 1))) * 8;

    f32x4 acc[2][2][4][2] = {};   // [qr][qc][fr][fc]

    auto stage_half = [&](int dbuf, int op, int half, int k0) {
        const ushort_t* P = (op == 0) ? Abf : Wbf;
        const int rowbase = ((op == 0) ? bm : bn) + half * 128;
        char* dbase = smem + dbuf * 65536 + op * 32768 + half * 16384 + wid * 1024;
        #pragma unroll
        for (int j = 0; j < 2; ++j) {
            const int s = j * 8 + wid;
            const ushort_t* gsrc = P + (size_t)(rowbase + (s >> 1) * 16 + srow4) * D_MODEL
                                     + k0 + (s & 1) * 32 + schunk;
            __builtin_amdgcn_global_load_lds((gvoid_t*)gsrc, (lvoid_t*)(dbase + j * 8192), 16, 0, 0);
        }
    };

    const int NT = D_MODEL / 64;   // 16 K-tiles
    // prologue: tile 0 into dbuf0, issue order A0, B0, B1, A1
    stage_half(0, 0, 0, 0);
    stage_half(0, 1, 0, 0);
    stage_half(0, 1, 1, 0);
    stage_half(0, 0, 1, 0);

    bf16x8 af[4][2], bA[2][2], bB[2][2];

#define MFMA16(QR, QC, BARR)                                                        \
    __builtin_amdgcn_s_setprio(1);                                                  \
    _Pragma("unroll")                                                               \
    for (int fr = 0; fr < 4; ++fr)                                                  \
        _Pragma("unroll")                                                           \
        for (int fc = 0; fc < 2; ++fc)                                              \
            _Pragma("unroll")                                                       \
            for (int ks = 0; ks < 2; ++ks)                                          \
                acc[QR][QC][fr][fc] = __builtin_amdgcn_mfma_f32_16x16x32_bf16(      \
                    af[fr][ks], BARR[fc][ks], acc[QR][QC][fr][fc], 0, 0, 0);        \
    __builtin_amdgcn_s_setprio(0);

    for (int t = 0; t < NT; ++t) {
        const int db = t & 1;
        const int kn = (t + 1) * 64;
        const bool more = (t + 1 < NT);
        const char* base = smem + db * 65536;

        // ---- phase 0: quadrant (0,0) -- reads A-half0, B-half0
        wait_vmcnt<4>();                 // A0(t),B0(t) landed; B1,A1 may fly
        __builtin_amdgcn_s_barrier();
        {
            const char* Ab = base + wm * 8192 + rdswz;
            const char* Bb = base + 32768 + wn * 4096 + rdswz;
            #pragma unroll
            for (int fr = 0; fr < 4; ++fr)
                #pragma unroll
                for (int ks = 0; ks < 2; ++ks)
                    af[fr][ks] = *reinterpret_cast<const bf16x8*>(Ab + fr * 2048 + ks * 1024);
            #pragma unroll
            for (int fc = 0; fc < 2; ++fc)
                #pragma unroll
                for (int ks = 0; ks < 2; ++ks)
                    bA[fc][ks] = *reinterpret_cast<const bf16x8*>(Bb + fc * 2048 + ks * 1024);
        }
        if (more) stage_half(db ^ 1, 0, 0, kn);   // A0(t+1)
        MFMA16(0, 0, bA)

        // ---- phase 1: quadrant (0,1) -- reads B-half1 (af cached)
        if (more) wait_vmcnt<4>(); else wait_vmcnt<2>();   // B1(t) landed
        __builtin_amdgcn_s_barrier();
        {
            const char* Bb = base + 32768 + 16384 + wn * 4096 + rdswz;
            #pragma unroll
            for (int fc = 0; fc < 2; ++fc)
                #pragma unroll
                for (int ks = 0; ks < 2; ++ks)
                    bB[fc][ks] = *reinterpret_cast<const bf16x8*>(Bb + fc * 2048 + ks * 1024);
        }
        if (more) stage_half(db ^ 1, 1, 0, kn);   // B0(t+1)
        MFMA16(0, 1, bB)

        // ---- phase 2: quadrant (1,0) -- reads A-half1 (bA cached)
        if (more) wait_vmcnt<4>(); else wait_vmcnt<0>();   // A1(t) landed
        __builtin_amdgcn_s_barrier();
        {
            const char* Ab = base + 16384 + wm * 8192 + rdswz;
            #pragma unroll
            for (int fr = 0; fr < 4; ++fr)
                #pragma unroll
                for (int ks = 0; ks < 2; ++ks)
                    af[fr][ks] = *reinterpret_cast<const bf16x8*>(Ab + fr * 2048 + ks * 1024);
        }
        if (more) stage_half(db ^ 1, 1, 1, kn);   // B1(t+1)
        MFMA16(1, 0, bA)

        // ---- phase 3: quadrant (1,1) -- no new reads
        __builtin_amdgcn_s_barrier();
        if (more) stage_half(db ^ 1, 0, 1, kn);   // A1(t+1)
        MFMA16(1, 1, bB)
    }
#undef MFMA16

    // epilogue: split x_ssm / silu(gate)
    #pragma unroll
    for (int qr = 0; qr < 2; ++qr)
        #pragma unroll
        for (int qc = 0; qc < 2; ++qc)
            #pragma unroll
            for (int fr = 0; fr < 4; ++fr) {
                int row0 = bm + qr * 128 + wm * 64 + fr * 16 + g * 4;
                #pragma unroll
                for (int fc = 0; fc < 2; ++fc) {
                    int col = bn + qc * 128 + wn * 32 + fc * 16 + r16;
                    float b = bias[col];
                    if (col < D_INNER) {
                        #pragma unroll
                        for (int jj = 0; jj < 4; ++jj)
                            out_x[(size_t)(row0 + jj) * D_INNER + col] = f2bf(acc[qr][qc][fr][fc][jj] + b);
                    } else {
                        int c2 = col - D_INNER;
                        #pragma unroll
                        for (int jj = 0; jj < 4; ++jj)
                            out_g[(size_t)(row0 + jj) * D_INNER + c2] = f2bf(silu_f(acc[qr][qc][fr][fc][jj] + b));
                    }
                }
            }
}

// ---------------------------------------------------------------------------
// out_proj GEMM (round-9 proven): depth-3 pipelined, counted vmcnt, BK=32,
// row-major LDS (coalesced staging).  C = A * W^T + bias -> f32.
// ---------------------------------------------------------------------------
#define BK 32

template <int BMt, int BNt>
__global__ __launch_bounds__(256) void gemm_pipe(
    const ushort_t* __restrict__ Abf, const ushort_t* __restrict__ Wbf,
    const float* __restrict__ bias,
    float* __restrict__ out0, int M, int N, int K)
{
    using bf16x8 = __attribute__((ext_vector_type(8))) short;
    using f32x4  = __attribute__((ext_vector_type(4))) float;

    constexpr int MF   = BMt / 32;
    constexpr int NF   = BNt / 32;
    constexpr int NBLK = (BMt + BNt) / 16;
    constexpr int TILE = (BMt + BNt) * 32;
    constexpr int L    = NBLK / 4;

    __shared__ ushort_t buf[3][TILE];

    const int tid  = threadIdx.x;
    const int lane = tid & 63;
    const int wid  = tid >> 6;
    const int bm   = blockIdx.y * BMt;
    const int bn   = blockIdx.x * BNt;
    const int wr   = (wid >> 1) * (BMt / 2);
    const int wc   = (wid & 1) * (BNt / 2);
    const int r16  = lane & 15;
    const int g    = lane >> 4;
    const int srow = lane >> 2;
    const int scol = (lane & 3) * 8;

    f32x4 acc[MF][NF] = {};

    auto stage = [&](int p, int k0) {
        #pragma unroll
        for (int i = wid; i < NBLK; i += 4) {
            const ushort_t* gsrc;
            if (i < BMt / 16)
                gsrc = Abf + (size_t)(bm + 16 * i + srow) * K + k0 + scol;
            else
                gsrc = Wbf + (size_t)(bn + 16 * (i - BMt / 16) + srow) * K + k0 + scol;
            __builtin_amdgcn_global_load_lds((gvoid_t*)gsrc, (lvoid_t*)(&buf[p][i * 512]), 16, 0, 0);
        }
    };

    const int NT = K / BK;
    stage(0, 0);
    stage(1, BK);
    wait_vmcnt<L>();
    __builtin_amdgcn_s_barrier();

    int cur = 0, s2 = 2;
    for (int t = 0; t < NT; ++t) {
        if (t + 2 < NT) stage(s2, (t + 2) * BK);

        const ushort_t* As = &buf[cur][0];
        const ushort_t* Bs = &buf[cur][BMt * 32];
        bf16x8 af[MF], bfr[NF];
        #pragma unroll
        for (int m = 0; m < MF; ++m)
            af[m] = *reinterpret_cast<const bf16x8*>(&As[(wr + m * 16 + r16) * BK + g * 8]);
        #pragma unroll
        for (int n = 0; n < NF; ++n)
            bfr[n] = *reinterpret_cast<const bf16x8*>(&Bs[(wc + n * 16 + r16) * BK + g * 8]);

        #pragma unroll
        for (int m = 0; m < MF; ++m)
            #pragma unroll
            for (int n = 0; n < NF; ++n)
                acc[m][n] = __builtin_amdgcn_mfma_f32_16x16x32_bf16(af[m], bfr[n], acc[m][n], 0, 0, 0);

        if (t + 1 < NT) {
            if (t + 2 < NT) wait_vmcnt<L>();
            else            wait_vmcnt<0>();
            __builtin_amdgcn_s_barrier();
        }
        cur = (cur + 1 == 3) ? 0 : cur + 1;
        s2  = (s2  + 1 == 3) ? 0 : s2  + 1;
    }

    #pragma unroll
    for (int m = 0; m < MF; ++m) {
        int row0 = bm + wr + m * 16 + g * 4;
        #pragma unroll
        for (int n = 0; n < NF; ++n) {
            int col = bn + wc + n * 16 + r16;
            float b = bias[col];
            #pragma unroll
            for (int jj = 0; jj < 4; ++jj)
                out0[(size_t)(row0 + jj) * N + col] = acc[m][n][jj] + b;
        }
    }
}

// ---------------------------------------------------------------------------
// Causal depthwise conv (D_CONV=4) + SiLU.  bf16 in, bf16 out.
// ---------------------------------------------------------------------------
__global__ __launch_bounds__(256) void conv_silu_kernel(
    const ushort_t* __restrict__ xssm,
    const float* __restrict__ conv_w,
    const float* __restrict__ conv_b,
    ushort_t* __restrict__ xc)
{
    int idx4 = blockIdx.x * 256 + threadIdx.x;
    if (idx4 >= NROWS * D_INNER / 4) return;
    size_t e = (size_t)idx4 * 4;
    int c   = (int)(e % D_INNER);
    int row = (int)(e / D_INNER);
    int s = row % SEQ;

    float4 wv[4];
    #pragma unroll
    for (int cc = 0; cc < 4; ++cc)
        wv[cc] = *reinterpret_cast<const float4*>(conv_w + (c + cc) * 4);
    float4 bv = *reinterpret_cast<const float4*>(conv_b + c);
    float acc[4] = {bv.x, bv.y, bv.z, bv.w};

    #pragma unroll
    for (int dt = 0; dt < 4; ++dt) {
        if (s >= dt) {
            ushort4 xv = *reinterpret_cast<const ushort4*>(xssm + (size_t)(row - dt) * D_INNER + c);
            acc[0] += (&wv[0].x)[3 - dt] * bf2f(xv.x);
            acc[1] += (&wv[1].x)[3 - dt] * bf2f(xv.y);
            acc[2] += (&wv[2].x)[3 - dt] * bf2f(xv.z);
            acc[3] += (&wv[3].x)[3 - dt] * bf2f(xv.w);
        }
    }
    ushort4 h;
    h.x = f2bf(silu_f(acc[0]));
    h.y = f2bf(silu_f(acc[1]));
    h.z = f2bf(silu_f(acc[2]));
    h.w = f2bf(silu_f(acc[3]));
    *reinterpret_cast<ushort4*>(xc + e) = h;
}

// ---------------------------------------------------------------------------
// XB = xconv (4096,2048) @ B(64,2048)^T -> (4096,64), bf16 MFMA.
// ---------------------------------------------------------------------------
__global__ __launch_bounds__(128) void xb_mfma(
    const ushort_t* __restrict__ xc, const ushort_t* __restrict__ Bw,
    float* __restrict__ xb)
{
    using bf16x8 = __attribute__((ext_vector_type(8))) short;
    using f32x4  = __attribute__((ext_vector_type(4))) float;

    __shared__ ushort_t As[32 * BK];
    __shared__ ushort_t Bs[64 * BK];

    const int tid  = threadIdx.x;
    const int lane = tid & 63;
    const int wid  = tid >> 6;
    const int bm   = blockIdx.x * 32;
    const int r16  = lane & 15;
    const int g    = lane >> 4;
    const int srow = lane >> 2;
    const int scol = (lane & 3) * 8;

    f32x4 acc[4] = {};

    for (int k0 = 0; k0 < D_INNER; k0 += BK) {
        const ushort_t* ga = xc + (size_t)(bm + 16 * wid + srow) * D_INNER + k0 + scol;
        __builtin_amdgcn_global_load_lds((gvoid_t*)ga, (lvoid_t*)(As + wid * 512), 16, 0, 0);
        #pragma unroll
        for (int ii = 0; ii < 2; ++ii) {
            int i = wid * 2 + ii;
            const ushort_t* gb = Bw + (size_t)(16 * i + srow) * D_INNER + k0 + scol;
            __builtin_amdgcn_global_load_lds((gvoid_t*)gb, (lvoid_t*)(Bs + i * 512), 16, 0, 0);
        }
        __syncthreads();

        bf16x8 a = *reinterpret_cast<const bf16x8*>(&As[(wid * 16 + r16) * BK + g * 8]);
        #pragma unroll
        for (int n = 0; n < 4; ++n) {
            bf16x8 bv = *reinterpret_cast<const bf16x8*>(&Bs[(n * 16 + r16) * BK + g * 8]);
            acc[n] = __builtin_amdgcn_mfma_f32_16x16x32_bf16(a, bv, acc[n], 0, 0, 0);
        }
        __syncthreads();
    }

    #pragma unroll
    for (int n = 0; n < 4; ++n) {
        int col  = n * 16 + r16;
        int row0 = bm + wid * 16 + g * 4;
        #pragma unroll
        for (int jj = 0; jj < 4; ++jj)
            xb[(size_t)(row0 + jj) * D_STATE + col] = acc[n][jj];
    }
}

// ---------------------------------------------------------------------------
// Speculative chunked tanh scan (overlap-save), C=W=32 (64 serial steps).
// ---------------------------------------------------------------------------
#define SCAN_C 32
#define SCAN_W 32
#define NCHUNK (SEQ / SCAN_C)   // 64

__global__ __launch_bounds__(64) void scan_kernel(const float* __restrict__ xb,
                                                  const float* __restrict__ A,
                                                  float* __restrict__ hall)
{
    using f32x4 = __attribute__((ext_vector_type(4))) float;

    __shared__ float xs[(SCAN_C + SCAN_W) * D_STATE];   // 16 KB
    __shared__ float hs[D_STATE];

    const int blk = blockIdx.x;
    const int b = blk >> 6;
    const int c = blk & (NCHUNK - 1);
    const int j = threadIdx.x;

    const int t0     = (c == 0) ? 0 : (c * SCAN_C - SCAN_W);
    const int warm   = c * SCAN_C - t0;        // 0 or 32
    const int nsteps = warm + SCAN_C;          // 32 or 64

    f32x4 areg[16];
    {
        const f32x4* arow = reinterpret_cast<const f32x4*>(A + j * D_STATE);
        #pragma unroll
        for (int q = 0; q < 16; ++q) areg[q] = arow[q];
    }

    const float* src = xb   + ((size_t)b * SEQ + t0) * D_STATE;
    float*       dst = hall + ((size_t)b * SEQ + c * SCAN_C) * D_STATE;

    const int nld = nsteps * D_STATE / 256;
    for (int i = 0; i < nld; ++i)
        __builtin_amdgcn_global_load_lds((gvoid_t*)(src + i * 256 + j * 4),
                                         (lvoid_t*)(&xs[i * 256]), 16, 0, 0);
    asm volatile("s_waitcnt vmcnt(0)" ::: "memory");

    hs[j] = 0.f;
    float h = 0.f;
    const f32x4* hp = reinterpret_cast<const f32x4*>(hs);

#define SCAN_STEP(t)                                                     \
    {                                                                    \
        float xv = xs[(t) * D_STATE + j];                                \
        f32x4 a0 = {xv, 0.f, 0.f, 0.f}, a1 = {0.f, 0.f, 0.f, 0.f};      \
        _Pragma("unroll")                                                \
        for (int q = 0; q < 16; q += 2) {                                \
            a0 += areg[q + 0] * hp[q + 0];                               \
            a1 += areg[q + 1] * hp[q + 1];                               \
        }                                                                \
        f32x4 s4 = a0 + a1;                                              \
        float s = (s4[0] + s4[1]) + (s4[2] + s4[3]);                     \
        float e = __expf(2.f * s);                                       \
        h = 1.f - 2.f * __builtin_amdgcn_rcpf(e + 1.f);                  \
        hs[j] = h;                                                       \
    }

    for (int t = 0; t < warm; ++t) {
        SCAN_STEP(t);
    }
    for (int t = warm; t < nsteps; ++t) {
        SCAN_STEP(t);
        dst[(size_t)(t - warm) * D_STATE + j] = h;
    }
#undef SCAN_STEP
}

// ---------------------------------------------------------------------------
// y = H @ C^T + xconv*D; x_out(bf16) = y * silu_gate(bf16)
// ---------------------------------------------------------------------------
__global__ __launch_bounds__(256) void ymul_kernel(
    const float* __restrict__ hall,
    const float* __restrict__ Cw,
    const float* __restrict__ Dv,
    const ushort_t* __restrict__ xc,
    const ushort_t* __restrict__ xg,
    ushort_t* __restrict__ xout)
{
    __shared__ float hs[16][D_STATE];
    int row0 = blockIdx.x * 16;
    int col  = blockIdx.y * 256 + threadIdx.x;
    int tid = threadIdx.x;
    const float4* src = reinterpret_cast<const float4*>(hall + (size_t)row0 * D_STATE);
    float4* dst = reinterpret_cast<float4*>(&hs[0][0]);
    dst[tid] = src[tid];
    __syncthreads();

    float creg[D_STATE];
    #pragma unroll
    for (int k = 0; k < D_STATE; k += 4) {
        float4 v = *reinterpret_cast<const float4*>(Cw + (size_t)col * D_STATE + k);
        creg[k] = v.x; creg[k + 1] = v.y; creg[k + 2] = v.z; creg[k + 3] = v.w;
    }
    float dv = Dv[col];
    #pragma unroll 4
    for (int r = 0; r < 16; ++r) {
        float a0 = 0, a1 = 0, a2 = 0, a3 = 0;
        #pragma unroll
        for (int k = 0; k < D_STATE; k += 4) {
            a0 += hs[r][k + 0] * creg[k + 0];
            a1 += hs[r][k + 1] * creg[k + 1];
            a2 += hs[r][k + 2] * creg[k + 2];
            a3 += hs[r][k + 3] * creg[k + 3];
        }
        size_t idx = (size_t)(row0 + r) * D_INNER + col;
        float y = (a0 + a1) + (a2 + a3) + bf2f(xc[idx]) * dv;
        xout[idx] = f2bf(y * bf2f(xg[idx]));
    }
}

// ---------------------------------------------------------------------------
extern "C" void kernel_launch(void* const* d_in, const int* in_sizes, int n_in,
                              void* d_out, int out_size, void* d_ws, size_t ws_size,
                              hipStream_t stream)
{
    const float* x          = (const float*)d_in[0];
    const float* in_proj_w  = (const float*)d_in[1];
    const float* in_proj_b  = (const float*)d_in[2];
    const float* conv_w     = (const float*)d_in[3];
    const float* conv_b     = (const float*)d_in[4];
    const float* A          = (const float*)d_in[5];
    const float* B          = (const float*)d_in[6];
    const float* C          = (const float*)d_in[7];
    const float* D          = (const float*)d_in[8];
    const float* out_proj_w = (const float*)d_in[9];
    const float* out_proj_b = (const float*)d_in[10];
    float* out = (float*)d_out;

    char* ws = (char*)d_ws;
    ushort_t* xg_bf   = (ushort_t*)(ws + 0);             // 16,777,216
    ushort_t* xc_bf   = (ushort_t*)(ws + 16777216);      // 16,777,216
    ushort_t* xssm_bf = (ushort_t*)(ws + 33554432);      // 16,777,216 (dead after conv)
    ushort_t* x_bf    = (ushort_t*)(ws + 50331648);      //  8,388,608 (dead after in_proj)
    ushort_t* w1_bf   = (ushort_t*)(ws + 58720256);      //  8,388,608 (dead after in_proj)
    ushort_t* xout_bf = (ushort_t*)(ws + 50331648);      // 16,777,216 (reuses x_bf+w1_bf)
    ushort_t* w2_bf   = (ushort_t*)(ws + 67108864);      //  4,194,304
    ushort_t* B_bf    = (ushort_t*)(ws + 71303168);      //    262,144
    float*    xb      = (float*)(ws + 71565312);         //  1,048,576
    float*    hall    = (float*)(ws + 72613888);         //  1,048,576

    // 1. all f32 -> bf16 conversions, one launch
    {
        int b0 = NROWS * D_MODEL / 1024;
        int b1 = 2 * D_INNER * D_MODEL / 1024;
        int b2 = D_MODEL * D_INNER / 1024;
        int b3 = D_STATE * D_INNER / 1024;
        cvt4_kernel<<<b0 + b1 + b2 + b3, 256, 0, stream>>>(
            x, x_bf, b0, in_proj_w, w1_bf, b1, out_proj_w, w2_bf, b2, B, B_bf, b3);
    }
    // 2. in_proj GEMM: 8-phase 256x256x64 schedule, 128KB dynamic LDS
    gemm8p_inproj<<<256, 512, 131072, stream>>>(x_bf, w1_bf, in_proj_b, xssm_bf, xg_bf);
    // 3. conv + silu -> bf16
    conv_silu_kernel<<<NROWS * D_INNER / 1024, 256, 0, stream>>>(xssm_bf, conv_w, conv_b, xc_bf);
    // 4. XB via bf16 MFMA
    xb_mfma<<<NROWS / 32, 128, 0, stream>>>(xc_bf, B_bf, xb);
    // 5. speculative chunked scan (C=W=32)
    scan_kernel<<<BATCH * NCHUNK, 64, 0, stream>>>(xb, A, hall);
    // 6. y + D-skip + gate multiply -> bf16 x_out (2-D grid)
    {
        dim3 grid(NROWS / 16, D_INNER / 256);
        ymul_kernel<<<grid, 256, 0, stream>>>(hall, C, D, xc_bf, xg_bf, xout_bf);
    }
    // 7. out_proj GEMM (round-9 depth-3, 128x64, BK=32)
    {
        dim3 grid(D_MODEL / 64, NROWS / 128);
        gemm_pipe<128, 64><<<grid, 256, 0, stream>>>(xout_bf, w2_bf, out_proj_b,
                                                     out, NROWS, D_MODEL, D_INNER);
    }
}